// Round 5
// baseline (190.375 us; speedup 1.0000x reference)
//
#include <hip/hip_runtime.h>
#include <hip/hip_cooperative_groups.h>

namespace cg = cooperative_groups;

// Degenerate-reference algebra (verified R2/R4, absmax <= 0.0625):
//   out[b,t,n] = sum_d V_sum[b,d] * WoH[d,n] + bo[n]      (constant over t)
//   V_sum[b,:] = (sum_t x[b,t,:]) @ Wv + T*bv
//   WoH[d,n]   = sum_h Wo[64h+d, n]
// R4 post-mortem: 4 dispatches -> gaps/ramp dominate (kernels ~25 us of
// traffic inside an ~85 us controllable span). R5: single cooperative
// dispatch, 2 grid.sync()s, all serial loops <= 32 deep.

namespace {
constexpr int B   = 8;
constexpr int T   = 1000;
constexpr int D   = 1024;
constexpr int HD  = 64;
constexpr int TSZ = 32;     // t-rows per P1 block
constexpr int NSEG = 32;    // 32*32 = 1024 >= 1000
}

__global__ __launch_bounds__(256)
void fused_kernel(const float* __restrict__ x,  const float* __restrict__ Wv,
                  const float* __restrict__ bv, const float* __restrict__ Wo,
                  const float* __restrict__ bo, float* __restrict__ out,
                  float* __restrict__ partial,  float* __restrict__ WoH,
                  float* __restrict__ vsp)
{
    cg::grid_group grid = cg::this_grid();
    __shared__ float sA[512];
    __shared__ float sB[256];
    __shared__ float sC[HD];
    const int t   = threadIdx.x;
    const int blk = blockIdx.x;

    // ---- P1: x partial sums (all 256 blocks) + WoH head-fold (1 entry/thr) ----
    {
        const int seg = blk & 31, b = blk >> 5;
        const int t0  = seg * TSZ;
        const int tn  = min(TSZ, T - t0);
        const int c4  = t * 4;
        float4 acc = make_float4(0.f, 0.f, 0.f, 0.f);
        const float* base = x + ((size_t)b * T + t0) * D + c4;
        for (int i = 0; i < tn; ++i) {
            const float4 v = *(const float4*)(base + (size_t)i * D);
            acc.x += v.x; acc.y += v.y; acc.z += v.z; acc.w += v.w;
        }
        *(float4*)(partial + ((size_t)seg * B + b) * D + c4) = acc;

        const int gtid = blk * 256 + t;            // 0..65535 == HD*D
        const int d = gtid >> 10, n = gtid & 1023;
        float w = 0.f;
        #pragma unroll
        for (int h = 0; h < 16; ++h)
            w += Wo[(size_t)(h * HD + d) * D + n]; // coalesced over n
        WoH[gtid] = w;
    }
    grid.sync();

    // ---- P2 (blocks 0..63): xs chunk from partials, split-K dot with Wv ----
    if (blk < 64) {
        const int b = blk >> 3, kc = blk & 7;      // kc: 128-col c-chunk
        const int cl = t & 127, half = t >> 7;
        float a = 0.f;
        #pragma unroll
        for (int i = 0; i < 16; ++i) {
            const int s = half * 16 + i;
            a += partial[((size_t)s * B + b) * D + kc * 128 + cl];
        }
        sA[half * 128 + cl] = a;
        __syncthreads();
        if (t < 128) sB[t] = sA[t] + sA[128 + t];  // xs chunk (128 floats)
        __syncthreads();
        const int d = t & 63, sub = t >> 6;
        float acc = 0.f;
        #pragma unroll
        for (int i = 0; i < 32; ++i) {
            const int c = sub * 32 + i;
            acc = fmaf(sB[c], Wv[(size_t)(kc * 128 + c) * HD + d], acc);
        }
        sA[256 + sub * 64 + d] = acc;
        __syncthreads();
        if (sub == 0) {
            float v = sA[256 + d] + sA[320 + d] + sA[384 + d] + sA[448 + d];
            if (kc == 0) v += (float)T * bv[d];
            vsp[((size_t)kc * B + b) * HD + d] = v;
        }
    }
    grid.sync();

    // ---- P3 (all 256 blocks): vs reduce + ro slice + broadcast ----
    {
        const int b = blk >> 5, nq = (blk >> 3) & 3, tz = blk & 7;
        {
            const int kc0 = t >> 6, d = t & 63;
            sA[t]       = vsp[((size_t)kc0 * B + b) * HD + d];
            sA[256 + t] = vsp[((size_t)(kc0 + 4) * B + b) * HD + d];
        }
        __syncthreads();
        if (t < HD) {
            float v = 0.f;
            #pragma unroll
            for (int kc = 0; kc < 8; ++kc) v += sA[kc * 64 + t];
            sC[t] = v;                              // V_sum[b][t]
        }
        __syncthreads();
        const int n = nq * 256 + t;
        float acc = bo[n];
        #pragma unroll
        for (int d = 0; d < HD; ++d)
            acc = fmaf(sC[d], WoH[d * D + n], acc); // sC: LDS broadcast
        sB[t] = acc;                                // ro slice (256 cols)
        __syncthreads();
        const int c4 = t & 63;                      // constant per thread
        const float4 val = *(const float4*)&sB[c4 * 4];
        const int r0 = tz * 125;
        for (int idx = t; idx < 125 * 64; idx += 256) {
            const int r = idx >> 6;
            *(float4*)(out + ((size_t)b * T + r0 + r) * D + nq * 256 + c4 * 4) = val;
        }
    }
}

// ---------------------------------------------------------------------------
extern "C" void kernel_launch(void* const* d_in, const int* in_sizes, int n_in,
                              void* d_out, int out_size, void* d_ws, size_t ws_size,
                              hipStream_t stream)
{
    const float* x  = (const float*)d_in[0];
    const float* Wv = (const float*)d_in[5];
    const float* bv = (const float*)d_in[6];
    const float* Wo = (const float*)d_in[7];
    const float* bo = (const float*)d_in[8];
    float* out = (float*)d_out;

    // ws layout (floats): partial[32*8*1024] | WoH[64*1024] | vsp[8*8*64]
    float* partial = (float*)d_ws;
    float* WoH = partial + (size_t)NSEG * B * D;
    float* vsp = WoH + (size_t)HD * D;

    void* args[] = {(void*)&x, (void*)&Wv, (void*)&bv, (void*)&Wo, (void*)&bo,
                    (void*)&out, (void*)&partial, (void*)&WoH, (void*)&vsp};
    hipLaunchCooperativeKernel((void*)fused_kernel, dim3(256), dim3(256),
                               args, 0, stream);
}

// Round 6
// 128.457 us; speedup vs baseline: 1.4820x; 1.4820x over previous
//
#include <hip/hip_runtime.h>

// Degenerate-reference algebra (verified R2/R4/R5, absmax <= 0.0625):
//   out[b,t,n] = sum_d V_sum[b,d] * WoH[d,n] + bo[n]      (constant over t)
//   V_sum[b,:] = (sum_t x[b,t,:]) @ Wv + T*bv
//   WoH[d,n]   = sum_h Wo[64h+d, n]
// R5 post-mortem: cooperative 1-dispatch ran 86 us (occ 10.6%, 618 GB/s) +
// ~35 us coop-launch overhead -> 190 us total. Plain-dispatch gap ~10-12 us
// each; fixed harness tax ~70 us. R6: TWO plain dispatches, wide grids,
// K2 redundantly recomputes V_sum per block from L2-resident intermediates.

namespace {
constexpr int B    = 8;
constexpr int T    = 1000;
constexpr int D    = 1024;
constexpr int HD   = 64;
constexpr int TSZ  = 32;    // t-rows per partial segment
constexpr int NSEG = 32;    // 32*32 = 1024 >= 1000
}

// ---------------------------------------------------------------------------
// K1 (512 blocks):
//   blocks 0..255   : partial[(seg*B+b)*D + c] = sum_{t in seg} x[b,t,c]
//   blocks 256..511 : WoH[d*D+n] = sum_h Wo[(h*HD+d)*D + n]
// ---------------------------------------------------------------------------
__global__ __launch_bounds__(256)
void stage1_kernel(const float* __restrict__ x, const float* __restrict__ Wo,
                   float* __restrict__ partial, float* __restrict__ WoH)
{
    const int blk = blockIdx.x;
    const int t   = threadIdx.x;
    if (blk < 256) {
        const int seg = blk & 31, b = blk >> 5;
        const int t0  = seg * TSZ;
        const int tn  = min(TSZ, T - t0);
        const int c4  = t * 4;
        float4 acc = make_float4(0.f, 0.f, 0.f, 0.f);
        const float* base = x + ((size_t)b * T + t0) * D + c4;
        for (int i = 0; i < tn; ++i) {
            const float4 v = *(const float4*)(base + (size_t)i * D);
            acc.x += v.x; acc.y += v.y; acc.z += v.z; acc.w += v.w;
        }
        *(float4*)(partial + ((size_t)seg * B + b) * D + c4) = acc;
    } else {
        const int gtid = (blk - 256) * 256 + t;     // 0..65535 == HD*D
        const int d = gtid >> 10, n = gtid & 1023;
        float w = 0.f;
        #pragma unroll
        for (int h = 0; h < 16; ++h)
            w += Wo[(size_t)(h * HD + d) * D + n];  // coalesced over n
        WoH[gtid] = w;
    }
}

// ---------------------------------------------------------------------------
// K2 (grid 4 x 8 x 16 = 512 blocks): per block (nq, b, tz):
//   A: xs[0..1023] = sum_seg partial  (LDS, one float4/thread, 32-deep)
//   B: vs[d] = xs . Wv[:,d] + T*bv[d] (split-4 over c, LDS reduce)
//   C: ro[n] = vs . WoH[:,n] + bo[n]  (64-deep, n = nq*256 + t)
//   D: stream 63 rows (last 55) of out[b, tz-chunk, nq-slice] as float4
// partial (1 MB), Wv (256 KB), WoH (256 KB) are L2/L3-resident -> redundant
// per-block recompute costs ~3 us aggregate, buys dispatch-count = 2.
// ---------------------------------------------------------------------------
__global__ __launch_bounds__(256)
void stage2_kernel(const float* __restrict__ partial, const float* __restrict__ Wv,
                   const float* __restrict__ bv, const float* __restrict__ WoH,
                   const float* __restrict__ bo, float* __restrict__ out)
{
    __shared__ float xs_l[D];          // 4 KB
    __shared__ float prt[4][HD];
    __shared__ float vs_l[HD];
    __shared__ float ro_l[256];
    const int nq = blockIdx.x;         // 0..3   (256-col n slice)
    const int b  = blockIdx.y;         // 0..7
    const int tz = blockIdx.z;         // 0..15  (t-row chunk of 63)
    const int t  = threadIdx.x;

    // --- A: rebuild xs for this b ---
    {
        const int c4 = t * 4;
        float4 acc = make_float4(0.f, 0.f, 0.f, 0.f);
        const float* p = partial + (size_t)b * D + c4;
        #pragma unroll
        for (int s = 0; s < NSEG; ++s) {
            const float4 v = *(const float4*)(p + (size_t)s * (B * D));
            acc.x += v.x; acc.y += v.y; acc.z += v.z; acc.w += v.w;
        }
        *(float4*)&xs_l[c4] = acc;
    }
    __syncthreads();

    // --- B: vs = xs @ Wv + T*bv  (4-way split over c) ---
    {
        const int d = t & 63, qr = t >> 6;
        const int c0 = qr * 256;
        float a = 0.f;
        for (int i = 0; i < 256; ++i)
            a = fmaf(xs_l[c0 + i], Wv[(size_t)(c0 + i) * HD + d], a);
        prt[qr][d] = a;
    }
    __syncthreads();
    if (t < HD)
        vs_l[t] = prt[0][t] + prt[1][t] + prt[2][t] + prt[3][t]
                + (float)T * bv[t];
    __syncthreads();

    // --- C: ro slice ---
    {
        const int n = nq * 256 + t;
        float acc = bo[n];
        #pragma unroll
        for (int d = 0; d < HD; ++d)
            acc = fmaf(vs_l[d], WoH[d * D + n], acc);  // vs_l: LDS broadcast
        ro_l[t] = acc;
    }
    __syncthreads();

    // --- D: broadcast rows ---
    {
        const int r0 = tz * 63;
        const int rn = min(63, T - r0);                // tz==15 -> 55
        const int c4 = (t & 63) * 4;                   // constant per thread
        const float4 val = *(const float4*)&ro_l[c4];
        float* obase = out + (size_t)b * T * D + nq * 256 + c4;
        for (int idx = t; idx < rn * 64; idx += 256) {
            const int r = idx >> 6;
            *(float4*)(obase + (size_t)(r0 + r) * D) = val;
        }
    }
}

// ---------------------------------------------------------------------------
extern "C" void kernel_launch(void* const* d_in, const int* in_sizes, int n_in,
                              void* d_out, int out_size, void* d_ws, size_t ws_size,
                              hipStream_t stream)
{
    const float* x  = (const float*)d_in[0];
    const float* Wv = (const float*)d_in[5];
    const float* bv = (const float*)d_in[6];
    const float* Wo = (const float*)d_in[7];
    const float* bo = (const float*)d_in[8];
    float* out = (float*)d_out;

    // ws layout (floats): partial[32*8*1024] (1 MB) | WoH[64*1024] (256 KB)
    float* partial = (float*)d_ws;
    float* WoH = partial + (size_t)NSEG * B * D;

    stage1_kernel<<<dim3(512),        256, 0, stream>>>(x, Wo, partial, WoH);
    stage2_kernel<<<dim3(4, B, 16),   256, 0, stream>>>(partial, Wv, bv, WoH,
                                                        bo, out);
}

// Round 7
// 127.980 us; speedup vs baseline: 1.4875x; 1.0037x over previous
//
#include <hip/hip_runtime.h>

// Degenerate-reference algebra (verified R2/R4/R5/R6, absmax <= 0.0625):
//   out[b,t,n] = sum_d V_sum[b,d] * WoH[d,n] + bo[n]      (constant over t)
//   V_sum[b,:] = (sum_t x[b,t,:]) @ Wv + T*bv
//   WoH[d,n]   = sum_h Wo[64h+d, n]
// R6 post-mortem: 128.5 us; K2's per-block rebuild of xs streamed the 1 MB
// partial array x512 blocks = 512 MB of cache traffic (~15 us). R7: shrink
// partial to 256 KB via in-block row-group reduction in K1 (8 segs x 4
// col-quarters, LDS reduce), K2 phase A becomes 8-deep / 128 MB aggregate.

namespace {
constexpr int B    = 8;
constexpr int T    = 1000;
constexpr int D    = 1024;
constexpr int HD   = 64;
constexpr int NSEG = 8;      // t-segments of 125 rows
constexpr int TSZ  = 125;
}

// ---------------------------------------------------------------------------
// K1 (320 blocks):
//  blocks 0..255  : (seg, b, qc) -> partial[(seg*B+b)*D + qc*256 .. +255]
//                   = sum_{t in seg} x[b,t,qc-slice]; 4 row-groups x 64
//                   float4-lanes, LDS reduce, one 1 KB write per block.
//  blocks 256..319: WoH[d*D+n] = sum_h Wo[(h*HD+d)*D+n]  (4 entries/thread)
// ---------------------------------------------------------------------------
__global__ __launch_bounds__(256)
void stage1_kernel(const float* __restrict__ x, const float* __restrict__ Wo,
                   float* __restrict__ partial, float* __restrict__ WoH)
{
    const int blk = blockIdx.x;
    const int t   = threadIdx.x;
    if (blk < 256) {
        __shared__ float4 red[4][64];
        const int seg = blk & 7;
        const int b   = (blk >> 3) & 7;
        const int qc  = blk >> 6;                  // 0..3
        const int rg  = t >> 6;                    // row group 0..3
        const int cl  = t & 63;                    // float4 lane
        const int t0  = seg * TSZ;
        float4 acc = make_float4(0.f, 0.f, 0.f, 0.f);
        const float* base = x + ((size_t)b * T + t0) * D + qc * 256 + cl * 4;
        for (int r = rg; r < TSZ; r += 4) {        // 31-32 iters, 1 KB/wave/iter
            const float4 v = *(const float4*)(base + (size_t)r * D);
            acc.x += v.x; acc.y += v.y; acc.z += v.z; acc.w += v.w;
        }
        red[rg][cl] = acc;
        __syncthreads();
        if (t < 64) {
            const float4 a0 = red[0][t], a1 = red[1][t];
            const float4 a2 = red[2][t], a3 = red[3][t];
            const float4 s = make_float4(a0.x + a1.x + a2.x + a3.x,
                                         a0.y + a1.y + a2.y + a3.y,
                                         a0.z + a1.z + a2.z + a3.z,
                                         a0.w + a1.w + a2.w + a3.w);
            *(float4*)(partial + ((size_t)(seg * B + b)) * D + qc * 256 + t * 4) = s;
        }
    } else {
        const int gtid = (blk - 256) * 256 + t;    // 0..16383
        #pragma unroll
        for (int e = 0; e < 4; ++e) {
            const int idx = e * 16384 + gtid;      // 0..65535 == HD*D
            const int d = idx >> 10, n = idx & 1023;
            float w = 0.f;
            #pragma unroll
            for (int h = 0; h < 16; ++h)
                w += Wo[(size_t)(h * HD + d) * D + n];   // coalesced over n
            WoH[idx] = w;
        }
    }
}

// ---------------------------------------------------------------------------
// K2 (grid 4 x 8 x 16 = 512 blocks): per block (nq, b, tz):
//   A: xs[1024] = sum_{s<8} partial[(s*B+b)*D + .]   (8-deep float4, L2-hot)
//   B: vs[d] = xs . Wv[:,d] + T*bv[d]                (split-4 over c)
//   C: ro[n] = vs . WoH[:,n] + bo[n]                 (64-deep)
//   D: stream 63 rows of out[b, tz-chunk, nq-slice] as float4
// ---------------------------------------------------------------------------
__global__ __launch_bounds__(256)
void stage2_kernel(const float* __restrict__ partial, const float* __restrict__ Wv,
                   const float* __restrict__ bv, const float* __restrict__ WoH,
                   const float* __restrict__ bo, float* __restrict__ out)
{
    __shared__ float xs_l[D];
    __shared__ float prt[4][HD];
    __shared__ float vs_l[HD];
    __shared__ float ro_l[256];
    const int nq = blockIdx.x;         // 0..3
    const int b  = blockIdx.y;         // 0..7
    const int tz = blockIdx.z;         // 0..15
    const int t  = threadIdx.x;

    // --- A ---
    {
        const int c4 = t * 4;
        float4 acc = make_float4(0.f, 0.f, 0.f, 0.f);
        const float* p = partial + (size_t)b * D + c4;
        #pragma unroll
        for (int s = 0; s < NSEG; ++s) {
            const float4 v = *(const float4*)(p + (size_t)s * (B * D));
            acc.x += v.x; acc.y += v.y; acc.z += v.z; acc.w += v.w;
        }
        *(float4*)&xs_l[c4] = acc;
    }
    __syncthreads();

    // --- B ---
    {
        const int d = t & 63, qr = t >> 6;
        const int c0 = qr * 256;
        float a = 0.f;
        for (int i = 0; i < 256; ++i)
            a = fmaf(xs_l[c0 + i], Wv[(size_t)(c0 + i) * HD + d], a);
        prt[qr][d] = a;
    }
    __syncthreads();
    if (t < HD)
        vs_l[t] = prt[0][t] + prt[1][t] + prt[2][t] + prt[3][t]
                + (float)T * bv[t];
    __syncthreads();

    // --- C ---
    {
        const int n = nq * 256 + t;
        float acc = bo[n];
        #pragma unroll
        for (int d = 0; d < HD; ++d)
            acc = fmaf(vs_l[d], WoH[d * D + n], acc);
        ro_l[t] = acc;
    }
    __syncthreads();

    // --- D ---
    {
        const int r0 = tz * 63;
        const int rn = min(63, T - r0);            // tz==15 -> 55
        const int c4 = (t & 63) * 4;
        const float4 val = *(const float4*)&ro_l[c4];
        float* obase = out + (size_t)b * T * D + nq * 256 + c4;
        for (int idx = t; idx < rn * 64; idx += 256) {
            const int r = idx >> 6;
            *(float4*)(obase + (size_t)(r0 + r) * D) = val;
        }
    }
}

// ---------------------------------------------------------------------------
extern "C" void kernel_launch(void* const* d_in, const int* in_sizes, int n_in,
                              void* d_out, int out_size, void* d_ws, size_t ws_size,
                              hipStream_t stream)
{
    const float* x  = (const float*)d_in[0];
    const float* Wv = (const float*)d_in[5];
    const float* bv = (const float*)d_in[6];
    const float* Wo = (const float*)d_in[7];
    const float* bo = (const float*)d_in[8];
    float* out = (float*)d_out;

    // ws layout (floats): partial[8*8*1024] (256 KB) | WoH[64*1024] (256 KB)
    float* partial = (float*)d_ws;
    float* WoH = partial + (size_t)NSEG * B * D;

    stage1_kernel<<<dim3(320),      256, 0, stream>>>(x, Wo, partial, WoH);
    stage2_kernel<<<dim3(4, B, 16), 256, 0, stream>>>(partial, Wv, bv, WoH,
                                                      bo, out);
}